// Round 11
// baseline (172.919 us; speedup 1.0000x reference)
//
#include <hip/hip_runtime.h>

#define NT 16384
#define D  2048
#define E  64
#define KCH 512           // K-chunk per wave (4 waves = full K)
#define TPC (KCH / 32)    // 16 k-tiles per chunk
#define NBLK (NT / 32)    // 512 blocks, 32 tokens each

typedef _Float16 half8 __attribute__((ext_vector_type(8)));
typedef float f32x4 __attribute__((ext_vector_type(4)));

// ---- prep: W[k][e] fp32 -> W^T hi/lo panes in MFMA-fragment order ----
// pane offset(k,e) = (((kc*TPC + t)*4 + m)*16 + c)*32 + g*8 + j
__global__ __launch_bounds__(256) void router_prep(const float* __restrict__ W,
                                                   _Float16* __restrict__ wthi,
                                                   _Float16* __restrict__ wtlo) {
    const int id  = blockIdx.x * 256 + threadIdx.x;  // 0..32767, grid 128
    const int k   = id >> 4;
    const int e4  = (id & 15) << 2;
    const int kc  = k / KCH;
    const int kr  = k % KCH;
    const int t   = kr >> 5;
    const int g   = (kr >> 3) & 3;
    const int j   = kr & 7;
    const float4 v = *(const float4*)&W[(size_t)k * E + e4];
    const float vv[4] = {v.x, v.y, v.z, v.w};
    #pragma unroll
    for (int i = 0; i < 4; ++i) {
        const int e = e4 + i;
        const int m = e >> 4, c = e & 15;
        const size_t off = ((((size_t)(kc * TPC + t) * 4 + m) * 16 + c) * 32) + g * 8 + j;
        float hf = (float)(_Float16)vv[i];
        hf = (fabsf(hf) < 6.1035156e-5f) ? 0.f : hf;   // FTZ guard
        wthi[off] = (_Float16)hf;
        wtlo[off] = (_Float16)((vv[i] - hf) * 2048.f);
    }
}

// ---- fused: GEMM (4 waves split K) + LDS reduce + top2/softmax epilogue ----
__global__ __launch_bounds__(256, 2) void router_fused(const float* __restrict__ x,
                                                       const _Float16* __restrict__ wthi,
                                                       const _Float16* __restrict__ wtlo,
                                                       const float* __restrict__ bias,
                                                       float* __restrict__ out,
                                                       float* __restrict__ psum_part,
                                                       float* __restrict__ cnt_part) {
    __shared__ __align__(16) float red[4][2][16][68];  // [kc][tt][c][e pad 68] = 34.8KB
    __shared__ float cnt[E];

    const int tid  = threadIdx.x;
    const int lane = tid & 63;
    const int w    = tid >> 6;     // wave = K-chunk 0..3
    const int g    = lane >> 4;
    const int c    = lane & 15;
    const int t0   = blockIdx.x * 32;

    if (tid < E) cnt[tid] = 0.f;

    const float* xp0 = &x[(size_t)(t0 + c) * D + w * KCH + g * 8];
    const float* xp1 = &x[(size_t)(t0 + 16 + c) * D + w * KCH + g * 8];
    const _Float16* whp = &wthi[(size_t)w * TPC * 2048 + c * 32 + g * 8];
    const _Float16* wlp = &wtlo[(size_t)w * TPC * 2048 + c * 32 + g * 8];

    f32x4 am[2][4], ac[2][4];
    #pragma unroll
    for (int tt = 0; tt < 2; ++tt)
        #pragma unroll
        for (int m = 0; m < 4; ++m) {
            am[tt][m] = (f32x4){0.f, 0.f, 0.f, 0.f};
            ac[tt][m] = (f32x4){0.f, 0.f, 0.f, 0.f};
        }

    float4 ca0 = *(const float4*)xp0, ca1 = *(const float4*)(xp0 + 4);
    float4 cb0 = *(const float4*)xp1, cb1 = *(const float4*)(xp1 + 4);

    #pragma unroll 1
    for (int t = 0; t < TPC; ++t) {
        float4 na0, na1, nb0, nb1;
        if (t + 1 < TPC) {   // uniform scalar branch; prefetch next x tile
            na0 = *(const float4*)(xp0 + (t + 1) * 32);
            na1 = *(const float4*)(xp0 + (t + 1) * 32 + 4);
            nb0 = *(const float4*)(xp1 + (t + 1) * 32);
            nb1 = *(const float4*)(xp1 + (t + 1) * 32 + 4);
        }
        half8 bh0, bl0, bh1, bl1;
        {
            const float xv0[8] = {ca0.x, ca0.y, ca0.z, ca0.w, ca1.x, ca1.y, ca1.z, ca1.w};
            const float xv1[8] = {cb0.x, cb0.y, cb0.z, cb0.w, cb1.x, cb1.y, cb1.z, cb1.w};
            #pragma unroll
            for (int j = 0; j < 8; ++j) {
                float h0 = (float)(_Float16)xv0[j];
                bh0[j] = (_Float16)h0;  bl0[j] = (_Float16)((xv0[j] - h0) * 2048.f);
                float h1 = (float)(_Float16)xv1[j];
                bh1[j] = (_Float16)h1;  bl1[j] = (_Float16)((xv1[j] - h1) * 2048.f);
            }
        }
        #pragma unroll
        for (int m = 0; m < 4; ++m) {
            const half8 ah = *(const half8*)(whp + (size_t)(t * 4 + m) * 512);
            const half8 al = *(const half8*)(wlp + (size_t)(t * 4 + m) * 512);
            am[0][m] = __builtin_amdgcn_mfma_f32_16x16x32_f16(ah, bh0, am[0][m], 0, 0, 0);
            ac[0][m] = __builtin_amdgcn_mfma_f32_16x16x32_f16(ah, bl0, ac[0][m], 0, 0, 0);
            ac[0][m] = __builtin_amdgcn_mfma_f32_16x16x32_f16(al, bh0, ac[0][m], 0, 0, 0);
            am[1][m] = __builtin_amdgcn_mfma_f32_16x16x32_f16(ah, bh1, am[1][m], 0, 0, 0);
            ac[1][m] = __builtin_amdgcn_mfma_f32_16x16x32_f16(ah, bl1, ac[1][m], 0, 0, 0);
            ac[1][m] = __builtin_amdgcn_mfma_f32_16x16x32_f16(al, bh1, ac[1][m], 0, 0, 0);
        }
        ca0 = na0; ca1 = na1; cb0 = nb0; cb1 = nb1;
    }

    // partials -> LDS
    #pragma unroll
    for (int tt = 0; tt < 2; ++tt)
        #pragma unroll
        for (int m = 0; m < 4; ++m) {
            f32x4 p;
            #pragma unroll
            for (int r = 0; r < 4; ++r) p[r] = am[tt][m][r] + ac[tt][m][r] * (1.f / 2048.f);
            *(f32x4*)&red[w][tt][c][m * 16 + g * 4] = p;
        }
    __syncthreads();

    if (w < 2) {
        // wave w handles tokens t0 + w*16 + c; lane(g,c) experts m*16+g*4+r
        const int tok = t0 + w * 16 + c;
        float lg[4][4];
        #pragma unroll
        for (int m = 0; m < 4; ++m) {
            f32x4 s = *(const f32x4*)&red[0][w][c][m * 16 + g * 4];
            #pragma unroll
            for (int kc = 1; kc < 4; ++kc) {
                const f32x4 q = *(const f32x4*)&red[kc][w][c][m * 16 + g * 4];
                #pragma unroll
                for (int r = 0; r < 4; ++r) s[r] += q[r];
            }
            #pragma unroll
            for (int r = 0; r < 4; ++r) lg[m][r] = s[r] + bias[m * 16 + g * 4 + r];
        }

        // local top-2 over this lane's 16 experts
        float v1 = -3.4e38f, v2 = -3.4e38f; int i1 = 0, i2 = 0;
        #pragma unroll
        for (int m = 0; m < 4; ++m)
            #pragma unroll
            for (int r = 0; r < 4; ++r) {
                const float v = lg[m][r];
                const int   e = m * 16 + g * 4 + r;
                if (v > v1) { v2 = v1; i2 = i1; v1 = v; i1 = e; }
                else if (v > v2) { v2 = v; i2 = e; }
            }
        // merge across the 4 lanes (g) holding this token
        #pragma unroll
        for (int mask = 16; mask <= 32; mask <<= 1) {
            const float ov1 = __shfl_xor(v1, mask, 64); const int oi1 = __shfl_xor(i1, mask, 64);
            const float ov2 = __shfl_xor(v2, mask, 64); const int oi2 = __shfl_xor(i2, mask, 64);
            const bool oTop = (ov1 > v1) || (ov1 == v1 && oi1 < i1);
            if (oTop) {
                const bool k2 = (v1 > ov2) || (v1 == ov2 && i1 < oi2);
                v2 = k2 ? v1 : ov2; i2 = k2 ? i1 : oi2;
                v1 = ov1; i1 = oi1;
            } else {
                const bool k2 = (ov1 > v2) || (ov1 == v2 && oi1 < i2);
                v2 = k2 ? ov1 : v2; i2 = k2 ? oi1 : i2;
            }
        }

        // softmax (max = v1)
        float s = 0.f;
        #pragma unroll
        for (int m = 0; m < 4; ++m)
            #pragma unroll
            for (int r = 0; r < 4; ++r) { lg[m][r] = expf(lg[m][r] - v1); s += lg[m][r]; }
        s += __shfl_xor(s, 16, 64);
        s += __shfl_xor(s, 32, 64);
        const float inv = 1.f / s;

        // normalized probs -> per-expert sums across this wave's 16 tokens
        #pragma unroll
        for (int m = 0; m < 4; ++m)
            #pragma unroll
            for (int r = 0; r < 4; ++r) {
                lg[m][r] *= inv;
                #pragma unroll
                for (int mask = 1; mask <= 8; mask <<= 1)
                    lg[m][r] += __shfl_xor(lg[m][r], mask, 64);
            }
        if (c == 0) {
            const int row = blockIdx.x * 2 + w;
            #pragma unroll
            for (int m = 0; m < 4; ++m)
                #pragma unroll
                for (int r = 0; r < 4; ++r)
                    psum_part[(size_t)row * E + m * 16 + g * 4 + r] = lg[m][r];
        }
        if (g == 0) {   // one leader lane per token
            const float p2 = expf(v2 - v1) * inv;
            out[tok * 2 + 0] = (float)i1;
            out[tok * 2 + 1] = (float)i2;
            out[2 * NT + tok * 2 + 0] = inv;     // p1 = exp(0)/s
            out[2 * NT + tok * 2 + 1] = p2;
            atomicAdd(&cnt[i1], 1.f);            // LDS atomic, block-local
            atomicAdd(&cnt[i2], 1.f);
        }
    }
    __syncthreads();
    if (tid < E) cnt_part[(size_t)blockIdx.x * E + tid] = cnt[tid];
}

// ---- parallel column reduce: 128 blocks, one expert-column each ----
__global__ __launch_bounds__(256) void router_aux1(const float* __restrict__ psum_part,
                                                   const float* __restrict__ cnt_part,
                                                   float* __restrict__ sums) {
    __shared__ float buf[256];
    const int j   = blockIdx.x;      // 0..63 psum col, 64..127 cnt col
    const int tid = threadIdx.x;
    float s = 0.f;
    if (j < E) {
        for (int r = tid; r < 2 * NBLK; r += 256) s += psum_part[(size_t)r * E + j];
    } else {
        const int e = j - E;
        for (int r = tid; r < NBLK; r += 256) s += cnt_part[(size_t)r * E + e];
    }
    buf[tid] = s;
    __syncthreads();
    #pragma unroll
    for (int step = 128; step >= 64; step >>= 1) {
        if (tid < step) buf[tid] += buf[tid + step];
        __syncthreads();
    }
    if (tid < 64) {
        float v = buf[tid];
        #pragma unroll
        for (int off = 32; off > 0; off >>= 1) v += __shfl_down(v, off);
        if (tid == 0) sums[j] = v;
    }
}

__global__ __launch_bounds__(64) void router_aux2(const float* __restrict__ sums,
                                                  float* __restrict__ out) {
    const int e = threadIdx.x;
    float v = sums[e] * sums[E + e] * (1.0f / NT) * (1.0f / NT);
    #pragma unroll
    for (int off = 32; off > 0; off >>= 1) v += __shfl_down(v, off);
    if (e == 0) out[NT * 2 * 2] = (float)E * v;
}

extern "C" void kernel_launch(void* const* d_in, const int* in_sizes, int n_in,
                              void* d_out, int out_size, void* d_ws, size_t ws_size,
                              hipStream_t stream) {
    const float* x = (const float*)d_in[0];
    const float* W = (const float*)d_in[1];
    const float* b = (const float*)d_in[2];
    float* out = (float*)d_out;

    // ws: | wthi 256KB | wtlo 256KB | psum_part 256KB | cnt_part 128KB | sums 512B |
    char* base = (char*)d_ws;
    _Float16* wthi = (_Float16*)base;
    _Float16* wtlo = wthi + (size_t)D * E;
    float* psum_part = (float*)(base + 2 * (size_t)D * E * sizeof(_Float16));
    float* cnt_part  = psum_part + (size_t)2 * NBLK * E;
    float* sums      = cnt_part + (size_t)NBLK * E;

    router_prep<<<dim3(128), dim3(256), 0, stream>>>(W, wthi, wtlo);
    // MEASUREMENT: launch fused 4x (idempotent). fused_warm = (dur - 54.3us) / 3.
    router_fused<<<dim3(NBLK), dim3(256), 0, stream>>>(x, wthi, wtlo, b, out,
                                                       psum_part, cnt_part);
    router_fused<<<dim3(NBLK), dim3(256), 0, stream>>>(x, wthi, wtlo, b, out,
                                                       psum_part, cnt_part);
    router_fused<<<dim3(NBLK), dim3(256), 0, stream>>>(x, wthi, wtlo, b, out,
                                                       psum_part, cnt_part);
    router_fused<<<dim3(NBLK), dim3(256), 0, stream>>>(x, wthi, wtlo, b, out,
                                                       psum_part, cnt_part);
    router_aux1<<<dim3(128), dim3(256), 0, stream>>>(psum_part, cnt_part, sums);
    router_aux2<<<dim3(1), dim3(64), 0, stream>>>(sums, out);
}

// Round 12
// 87.118 us; speedup vs baseline: 1.9849x; 1.9849x over previous
//
#include <hip/hip_runtime.h>

#define NT 16384
#define D  2048
#define E  64
#define BK 128             // k-floats staged per step
#define NSTEP (D / BK)     // 16
#define NBLK (NT / 32)     // 512 blocks, 32 tokens each
#define XROW 136           // padded halves per token row (272B -> 4-bank shift)

typedef _Float16 half8 __attribute__((ext_vector_type(8)));
typedef float f32x4 __attribute__((ext_vector_type(4)));

// ---- prep: W[k][e] fp32 -> W^T hi/lo panes in MFMA-fragment order (full-K, no chunking) ----
// pane offset(k,e) = ((kt*4 + m)*16 + c)*32 + g*8 + j   (kt = k/32, g=(k/8)&3, j=k&7, m=e/16, c=e&15)
__global__ __launch_bounds__(256) void router_prep(const float* __restrict__ W,
                                                   _Float16* __restrict__ wthi,
                                                   _Float16* __restrict__ wtlo) {
    const int id  = blockIdx.x * 256 + threadIdx.x;  // grid 128 -> 0..32767
    const int k   = id >> 4;
    const int e4  = (id & 15) << 2;
    const int t   = k >> 5;          // 0..63
    const int g   = (k >> 3) & 3;
    const int j   = k & 7;
    const float4 v = *(const float4*)&W[(size_t)k * E + e4];
    const float vv[4] = {v.x, v.y, v.z, v.w};
    #pragma unroll
    for (int i = 0; i < 4; ++i) {
        const int e = e4 + i;
        const int m = e >> 4, c = e & 15;
        const size_t off = (((size_t)(t * 4 + m) * 16 + c) * 32) + g * 8 + j;
        float hf = (float)(_Float16)vv[i];
        hf = (fabsf(hf) < 6.1035156e-5f) ? 0.f : hf;   // FTZ guard
        wthi[off] = (_Float16)hf;
        wtlo[off] = (_Float16)((vv[i] - hf) * 2048.f);
    }
}

// ---- fused: coalesced LDS-staged x, full-K per wave, fused epilogue ----
__global__ __launch_bounds__(256, 2) void router_fused(const float* __restrict__ x,
                                                       const _Float16* __restrict__ wthi,
                                                       const _Float16* __restrict__ wtlo,
                                                       const float* __restrict__ bias,
                                                       float* __restrict__ out,
                                                       float* __restrict__ psum_part,
                                                       float* __restrict__ cnt_part) {
    __shared__ _Float16 xp[2][2][32 * XROW];   // [buf][hi/lo][tok][k] = 34.8 KB
    __shared__ float cnt[E];

    const int tid  = threadIdx.x;
    const int lane = tid & 63;
    const int w    = tid >> 6;      // wave 0..3
    const int g    = lane >> 4;     // k-octet group
    const int c    = lane & 15;     // fragment col
    const int t0   = blockIdx.x * 32;

    if (tid < E) cnt[tid] = 0.f;

    // staging map: thread -> (token row, 16-float column chunk); 8 threads cover a 512B row chunk
    const int srow = tid >> 3;          // 0..31
    const int scol = (tid & 7) * 16;    // 0..112
    const float* xg = &x[(size_t)(t0 + srow) * D + scol];

    // wave roles: 16 tokens x 32 experts, full K
    const int mh = w >> 1;              // expert half
    const int tw = (w & 1) * 16;        // token base

    f32x4 am[2], ac[2];
    #pragma unroll
    for (int mi = 0; mi < 2; ++mi) {
        am[mi] = (f32x4){0.f, 0.f, 0.f, 0.f};
        ac[mi] = (f32x4){0.f, 0.f, 0.f, 0.f};
    }

    float xr[16];
    auto LOADX = [&](int s) {   // coalesced: 4x float4, 64B contiguous per thread
        const float* p = xg + s * BK;
        *(float4*)&xr[0]  = *(const float4*)(p);
        *(float4*)&xr[4]  = *(const float4*)(p + 4);
        *(float4*)&xr[8]  = *(const float4*)(p + 8);
        *(float4*)&xr[12] = *(const float4*)(p + 12);
    };
    auto STOREX = [&](int buf) {  // split hi/lo once, 16B-aligned b128 writes
        _Float16* ph = &xp[buf][0][srow * XROW + scol];
        _Float16* pl = &xp[buf][1][srow * XROW + scol];
        half8 h0, h1, l0, l1;
        #pragma unroll
        for (int j = 0; j < 8; ++j) {
            float v0 = xr[j],     hf0 = (float)(_Float16)v0;
            float v1 = xr[8 + j], hf1 = (float)(_Float16)v1;
            h0[j] = (_Float16)hf0;  l0[j] = (_Float16)((v0 - hf0) * 2048.f);
            h1[j] = (_Float16)hf1;  l1[j] = (_Float16)((v1 - hf1) * 2048.f);
        }
        *(half8*)ph       = h0;  *(half8*)(ph + 8) = h1;
        *(half8*)pl       = l0;  *(half8*)(pl + 8) = l1;
    };

    LOADX(0); STOREX(0); __syncthreads();

    #pragma unroll 1
    for (int s = 0; s < NSTEP; ++s) {
        if (s + 1 < NSTEP) LOADX(s + 1);
        const _Float16* bhp = &xp[s & 1][0][(tw + c) * XROW];
        const _Float16* blp = &xp[s & 1][1][(tw + c) * XROW];
        #pragma unroll
        for (int kt = 0; kt < 4; ++kt) {
            const int ka = s * 4 + kt;
            const half8 bh = *(const half8*)(bhp + kt * 32 + g * 8);
            const half8 bl = *(const half8*)(blp + kt * 32 + g * 8);
            #pragma unroll
            for (int mi = 0; mi < 2; ++mi) {
                const int m = mh * 2 + mi;
                const size_t o = (((size_t)(ka * 4 + m) * 16 + c) * 32) + g * 8;
                const half8 ah = *(const half8*)(wthi + o);
                const half8 al = *(const half8*)(wtlo + o);
                am[mi] = __builtin_amdgcn_mfma_f32_16x16x32_f16(ah, bh, am[mi], 0, 0, 0);
                ac[mi] = __builtin_amdgcn_mfma_f32_16x16x32_f16(ah, bl, ac[mi], 0, 0, 0);
                ac[mi] = __builtin_amdgcn_mfma_f32_16x16x32_f16(al, bh, ac[mi], 0, 0, 0);
            }
        }
        if (s + 1 < NSTEP) STOREX((s + 1) & 1);
        __syncthreads();
    }

    // logits -> LDS pane Ls[32][68] (exactly overlays xp[0][0], all reads done)
    float* Ls = (float*)&xp[0][0][0];
    #pragma unroll
    for (int mi = 0; mi < 2; ++mi) {
        const int m = mh * 2 + mi;
        f32x4 p;
        #pragma unroll
        for (int r = 0; r < 4; ++r)
            p[r] = am[mi][r] + ac[mi][r] * (1.f / 2048.f) + bias[m * 16 + g * 4 + r];
        *(f32x4*)&Ls[(tw + c) * 68 + m * 16 + g * 4] = p;
    }
    __syncthreads();

    if (w < 2) {
        const int tok = t0 + w * 16 + c;
        float lg[4][4];
        #pragma unroll
        for (int m = 0; m < 4; ++m) {
            const f32x4 q = *(const f32x4*)&Ls[(w * 16 + c) * 68 + m * 16 + g * 4];
            #pragma unroll
            for (int r = 0; r < 4; ++r) lg[m][r] = q[r];
        }

        // local top-2 over this lane's 16 experts
        float v1 = -3.4e38f, v2 = -3.4e38f; int i1 = 0, i2 = 0;
        #pragma unroll
        for (int m = 0; m < 4; ++m)
            #pragma unroll
            for (int r = 0; r < 4; ++r) {
                const float v = lg[m][r];
                const int   e = m * 16 + g * 4 + r;
                if (v > v1) { v2 = v1; i2 = i1; v1 = v; i1 = e; }
                else if (v > v2) { v2 = v; i2 = e; }
            }
        // merge across the 4 lanes (g) holding this token
        #pragma unroll
        for (int mask = 16; mask <= 32; mask <<= 1) {
            const float ov1 = __shfl_xor(v1, mask, 64); const int oi1 = __shfl_xor(i1, mask, 64);
            const float ov2 = __shfl_xor(v2, mask, 64); const int oi2 = __shfl_xor(i2, mask, 64);
            const bool oTop = (ov1 > v1) || (ov1 == v1 && oi1 < i1);
            if (oTop) {
                const bool k2 = (v1 > ov2) || (v1 == ov2 && i1 < oi2);
                v2 = k2 ? v1 : ov2; i2 = k2 ? i1 : oi2;
                v1 = ov1; i1 = oi1;
            } else {
                const bool k2 = (ov1 > v2) || (ov1 == v2 && oi1 < i2);
                v2 = k2 ? ov1 : v2; i2 = k2 ? oi1 : i2;
            }
        }

        // softmax (max = v1)
        float s = 0.f;
        #pragma unroll
        for (int m = 0; m < 4; ++m)
            #pragma unroll
            for (int r = 0; r < 4; ++r) { lg[m][r] = expf(lg[m][r] - v1); s += lg[m][r]; }
        s += __shfl_xor(s, 16, 64);
        s += __shfl_xor(s, 32, 64);
        const float inv = 1.f / s;

        // normalized probs -> per-expert sums across this wave's 16 tokens
        #pragma unroll
        for (int m = 0; m < 4; ++m)
            #pragma unroll
            for (int r = 0; r < 4; ++r) {
                lg[m][r] *= inv;
                #pragma unroll
                for (int mask = 1; mask <= 8; mask <<= 1)
                    lg[m][r] += __shfl_xor(lg[m][r], mask, 64);
            }
        if (c == 0) {
            const int row = blockIdx.x * 2 + w;
            #pragma unroll
            for (int m = 0; m < 4; ++m)
                #pragma unroll
                for (int r = 0; r < 4; ++r)
                    psum_part[(size_t)row * E + m * 16 + g * 4 + r] = lg[m][r];
        }
        if (g == 0) {   // one leader lane per token
            const float p2 = expf(v2 - v1) * inv;
            out[tok * 2 + 0] = (float)i1;
            out[tok * 2 + 1] = (float)i2;
            out[2 * NT + tok * 2 + 0] = inv;     // p1 = exp(0)/s
            out[2 * NT + tok * 2 + 1] = p2;
            atomicAdd(&cnt[i1], 1.f);            // LDS atomic, block-local
            atomicAdd(&cnt[i2], 1.f);
        }
    }
    __syncthreads();
    if (tid < E) cnt_part[(size_t)blockIdx.x * E + tid] = cnt[tid];
}

// ---- parallel column reduce: 128 blocks, one expert-column each ----
__global__ __launch_bounds__(256) void router_aux1(const float* __restrict__ psum_part,
                                                   const float* __restrict__ cnt_part,
                                                   float* __restrict__ sums) {
    __shared__ float buf[256];
    const int j   = blockIdx.x;      // 0..63 psum col, 64..127 cnt col
    const int tid = threadIdx.x;
    float s = 0.f;
    if (j < E) {
        for (int r = tid; r < 2 * NBLK; r += 256) s += psum_part[(size_t)r * E + j];
    } else {
        const int e = j - E;
        for (int r = tid; r < NBLK; r += 256) s += cnt_part[(size_t)r * E + e];
    }
    buf[tid] = s;
    __syncthreads();
    #pragma unroll
    for (int step = 128; step >= 64; step >>= 1) {
        if (tid < step) buf[tid] += buf[tid + step];
        __syncthreads();
    }
    if (tid < 64) {
        float v = buf[tid];
        #pragma unroll
        for (int off = 32; off > 0; off >>= 1) v += __shfl_down(v, off);
        if (tid == 0) sums[j] = v;
    }
}

__global__ __launch_bounds__(64) void router_aux2(const float* __restrict__ sums,
                                                  float* __restrict__ out) {
    const int e = threadIdx.x;
    float v = sums[e] * sums[E + e] * (1.0f / NT) * (1.0f / NT);
    #pragma unroll
    for (int off = 32; off > 0; off >>= 1) v += __shfl_down(v, off);
    if (e == 0) out[NT * 2 * 2] = (float)E * v;
}

extern "C" void kernel_launch(void* const* d_in, const int* in_sizes, int n_in,
                              void* d_out, int out_size, void* d_ws, size_t ws_size,
                              hipStream_t stream) {
    const float* x = (const float*)d_in[0];
    const float* W = (const float*)d_in[1];
    const float* b = (const float*)d_in[2];
    float* out = (float*)d_out;

    // ws: | wthi 256KB | wtlo 256KB | psum_part 256KB | cnt_part 128KB | sums 512B |
    char* base = (char*)d_ws;
    _Float16* wthi = (_Float16*)base;
    _Float16* wtlo = wthi + (size_t)D * E;
    float* psum_part = (float*)(base + 2 * (size_t)D * E * sizeof(_Float16));
    float* cnt_part  = psum_part + (size_t)2 * NBLK * E;
    float* sums      = cnt_part + (size_t)NBLK * E;

    router_prep<<<dim3(128), dim3(256), 0, stream>>>(W, wthi, wtlo);
    router_fused<<<dim3(NBLK), dim3(256), 0, stream>>>(x, wthi, wtlo, b, out,
                                                       psum_part, cnt_part);
    router_aux1<<<dim3(128), dim3(256), 0, stream>>>(psum_part, cnt_part, sums);
    router_aux2<<<dim3(1), dim3(64), 0, stream>>>(sums, out);
}

// Round 13
// 59.067 us; speedup vs baseline: 2.9275x; 1.4749x over previous
//
#include <hip/hip_runtime.h>

#define NT 16384
#define D  2048
#define E  64
#define S  8               // K-split factor
#define KCH (D / S)        // 256
#define TPC (KCH / 32)     // 8
#define NBLK2 (NT / 16)    // 1024 phase-2 blocks

typedef _Float16 half8 __attribute__((ext_vector_type(8)));
typedef float f32x4 __attribute__((ext_vector_type(4)));

// ---- prep: W[k][e] fp32 -> W^T hi/lo panes in MFMA-fragment order (R5-proven) ----
// pane offset(k,e) = (((kc*TPC + t)*4 + m)*16 + c)*32 + g*8 + j
__global__ __launch_bounds__(256) void router_prep(const float* __restrict__ W,
                                                   _Float16* __restrict__ wthi,
                                                   _Float16* __restrict__ wtlo) {
    const int id  = blockIdx.x * 256 + threadIdx.x;  // grid 128 -> 0..32767
    const int k   = id >> 4;
    const int e4  = (id & 15) << 2;
    const int kc  = k / KCH;
    const int kr  = k % KCH;
    const int t   = kr >> 5;
    const int g   = (kr >> 3) & 3;
    const int j   = kr & 7;
    const float4 v = *(const float4*)&W[(size_t)k * E + e4];
    const float vv[4] = {v.x, v.y, v.z, v.w};
    #pragma unroll
    for (int i = 0; i < 4; ++i) {
        const int e = e4 + i;
        const int m = e >> 4, c = e & 15;
        const size_t off = ((((size_t)(kc * TPC + t) * 4 + m) * 16 + c) * 32) + g * 8 + j;
        float hf = (float)(_Float16)vv[i];
        hf = (fabsf(hf) < 6.1035156e-5f) ? 0.f : hf;   // FTZ guard
        wthi[off] = (_Float16)hf;
        wtlo[off] = (_Float16)((vv[i] - hf) * 2048.f);
    }
}

// ---- phase 1 (R5-proven): independent waves, 32 tokens x K-chunk, no LDS/barriers ----
// partials: part[(((kc*4+m)*NT + tok) << 4) + g*4 + r]
__global__ __launch_bounds__(256, 3) void router_gemm(const float* __restrict__ x,
                                                      const _Float16* __restrict__ wthi,
                                                      const _Float16* __restrict__ wtlo,
                                                      float* __restrict__ part) {
    const int tid  = threadIdx.x;
    const int lane = tid & 63;
    const int w    = tid >> 6;
    const int g    = lane >> 4;
    const int c    = lane & 15;
    const int wid  = blockIdx.x * 4 + w;      // 0 .. (NT/32)*S - 1
    const int kc   = wid % S;
    const int tg   = wid / S;
    const int t0   = tg * 32;

    const float* xp0 = &x[(size_t)(t0 + c) * D + kc * KCH + g * 8];
    const float* xp1 = &x[(size_t)(t0 + 16 + c) * D + kc * KCH + g * 8];
    const _Float16* whp = &wthi[(size_t)kc * TPC * 2048 + c * 32 + g * 8];
    const _Float16* wlp = &wtlo[(size_t)kc * TPC * 2048 + c * 32 + g * 8];

    f32x4 am[2][4], ac[2][4];
    #pragma unroll
    for (int tt = 0; tt < 2; ++tt)
        #pragma unroll
        for (int m = 0; m < 4; ++m) {
            am[tt][m] = (f32x4){0.f, 0.f, 0.f, 0.f};
            ac[tt][m] = (f32x4){0.f, 0.f, 0.f, 0.f};
        }

    float4 ca0 = *(const float4*)xp0, ca1 = *(const float4*)(xp0 + 4);
    float4 cb0 = *(const float4*)xp1, cb1 = *(const float4*)(xp1 + 4);

    #pragma unroll 1
    for (int t = 0; t < TPC; ++t) {
        float4 na0, na1, nb0, nb1;
        if (t + 1 < TPC) {   // uniform scalar branch; prefetch next x tile
            na0 = *(const float4*)(xp0 + (t + 1) * 32);
            na1 = *(const float4*)(xp0 + (t + 1) * 32 + 4);
            nb0 = *(const float4*)(xp1 + (t + 1) * 32);
            nb1 = *(const float4*)(xp1 + (t + 1) * 32 + 4);
        }
        half8 bh0, bl0, bh1, bl1;
        {
            const float xv0[8] = {ca0.x, ca0.y, ca0.z, ca0.w, ca1.x, ca1.y, ca1.z, ca1.w};
            const float xv1[8] = {cb0.x, cb0.y, cb0.z, cb0.w, cb1.x, cb1.y, cb1.z, cb1.w};
            #pragma unroll
            for (int j = 0; j < 8; ++j) {
                float h0 = (float)(_Float16)xv0[j];
                bh0[j] = (_Float16)h0;  bl0[j] = (_Float16)((xv0[j] - h0) * 2048.f);
                float h1 = (float)(_Float16)xv1[j];
                bh1[j] = (_Float16)h1;  bl1[j] = (_Float16)((xv1[j] - h1) * 2048.f);
            }
        }
        #pragma unroll
        for (int m = 0; m < 4; ++m) {
            const half8 ah = *(const half8*)(whp + (size_t)(t * 4 + m) * 512);
            const half8 al = *(const half8*)(wlp + (size_t)(t * 4 + m) * 512);
            am[0][m] = __builtin_amdgcn_mfma_f32_16x16x32_f16(ah, bh0, am[0][m], 0, 0, 0);
            ac[0][m] = __builtin_amdgcn_mfma_f32_16x16x32_f16(ah, bl0, ac[0][m], 0, 0, 0);
            ac[0][m] = __builtin_amdgcn_mfma_f32_16x16x32_f16(al, bh0, ac[0][m], 0, 0, 0);
            am[1][m] = __builtin_amdgcn_mfma_f32_16x16x32_f16(ah, bh1, am[1][m], 0, 0, 0);
            ac[1][m] = __builtin_amdgcn_mfma_f32_16x16x32_f16(ah, bl1, ac[1][m], 0, 0, 0);
            ac[1][m] = __builtin_amdgcn_mfma_f32_16x16x32_f16(al, bh1, ac[1][m], 0, 0, 0);
        }
        ca0 = na0; ca1 = na1; cb0 = nb0; cb1 = nb1;
    }

    // store fp32 partials, fully coalesced
    #pragma unroll
    for (int tt = 0; tt < 2; ++tt) {
        const int tok = t0 + tt * 16 + c;
        #pragma unroll
        for (int m = 0; m < 4; ++m) {
            f32x4 p;
            #pragma unroll
            for (int r = 0; r < 4; ++r) p[r] = am[tt][m][r] + ac[tt][m][r] * (1.f / 2048.f);
            *(f32x4*)&part[(((size_t)(kc * 4 + m) * NT + tok) << 4) + g * 4] = p;
        }
    }
}

// ---- phase 2: 4-wave blocks, 16 tokens each; waves split S; LDS reduce; wave-0 epilogue ----
__global__ __launch_bounds__(256) void router_top(const float* __restrict__ part,
                                                  const float* __restrict__ bias,
                                                  float* __restrict__ out,
                                                  float* __restrict__ psum_part,
                                                  float* __restrict__ cnt_part) {
    __shared__ __align__(16) float red[4][16][68];   // [wave][c][e pad 68] = 17.4KB
    __shared__ float cnt[E];

    const int tid  = threadIdx.x;
    const int lane = tid & 63;
    const int w    = tid >> 6;      // wave 0..3 -> kc pair {2w, 2w+1}
    const int g    = lane >> 4;
    const int c    = lane & 15;
    const int tok  = blockIdx.x * 16 + c;

    // 8 independent coalesced loads (1KB/instr across wave), then combine
    f32x4 q[4][2];
    #pragma unroll
    for (int m = 0; m < 4; ++m)
        #pragma unroll
        for (int p = 0; p < 2; ++p) {
            const int kc = 2 * w + p;
            q[m][p] = *(const f32x4*)&part[(((size_t)(kc * 4 + m) * NT + tok) << 4) + g * 4];
        }
    #pragma unroll
    for (int m = 0; m < 4; ++m) {
        f32x4 s = q[m][0];
        #pragma unroll
        for (int r = 0; r < 4; ++r) s[r] += q[m][1][r];
        *(f32x4*)&red[w][c][m * 16 + g * 4] = s;
    }
    __syncthreads();

    if (w == 0) {
        cnt[lane] = 0.f;
        float lg[4][4];
        #pragma unroll
        for (int m = 0; m < 4; ++m) {
            f32x4 s = *(const f32x4*)&red[0][c][m * 16 + g * 4];
            #pragma unroll
            for (int kc = 1; kc < 4; ++kc) {
                const f32x4 v = *(const f32x4*)&red[kc][c][m * 16 + g * 4];
                #pragma unroll
                for (int r = 0; r < 4; ++r) s[r] += v[r];
            }
            #pragma unroll
            for (int r = 0; r < 4; ++r) lg[m][r] = s[r] + bias[m * 16 + g * 4 + r];
        }

        // local top-2 over this lane's 16 experts
        float v1 = -3.4e38f, v2 = -3.4e38f; int i1 = 0, i2 = 0;
        #pragma unroll
        for (int m = 0; m < 4; ++m)
            #pragma unroll
            for (int r = 0; r < 4; ++r) {
                const float v = lg[m][r];
                const int   e = m * 16 + g * 4 + r;
                if (v > v1) { v2 = v1; i2 = i1; v1 = v; i1 = e; }
                else if (v > v2) { v2 = v; i2 = e; }
            }
        // merge across the 4 lanes (g) holding this token
        #pragma unroll
        for (int mask = 16; mask <= 32; mask <<= 1) {
            const float ov1 = __shfl_xor(v1, mask, 64); const int oi1 = __shfl_xor(i1, mask, 64);
            const float ov2 = __shfl_xor(v2, mask, 64); const int oi2 = __shfl_xor(i2, mask, 64);
            const bool oTop = (ov1 > v1) || (ov1 == v1 && oi1 < i1);
            if (oTop) {
                const bool k2 = (v1 > ov2) || (v1 == ov2 && i1 < oi2);
                v2 = k2 ? v1 : ov2; i2 = k2 ? i1 : oi2;
                v1 = ov1; i1 = oi1;
            } else {
                const bool k2 = (ov1 > v2) || (ov1 == v2 && oi1 < i2);
                v2 = k2 ? ov1 : v2; i2 = k2 ? oi1 : i2;
            }
        }

        // softmax (max = v1)
        float s = 0.f;
        #pragma unroll
        for (int m = 0; m < 4; ++m)
            #pragma unroll
            for (int r = 0; r < 4; ++r) { lg[m][r] = expf(lg[m][r] - v1); s += lg[m][r]; }
        s += __shfl_xor(s, 16, 64);
        s += __shfl_xor(s, 32, 64);
        const float inv = 1.f / s;

        // normalized probs -> per-expert sums across these 16 tokens
        #pragma unroll
        for (int m = 0; m < 4; ++m)
            #pragma unroll
            for (int r = 0; r < 4; ++r) {
                lg[m][r] *= inv;
                #pragma unroll
                for (int mask = 1; mask <= 8; mask <<= 1)
                    lg[m][r] += __shfl_xor(lg[m][r], mask, 64);
            }
        if (c == 0) {
            #pragma unroll
            for (int m = 0; m < 4; ++m)
                #pragma unroll
                for (int r = 0; r < 4; ++r)
                    psum_part[(size_t)blockIdx.x * E + m * 16 + g * 4 + r] = lg[m][r];
        }
        if (g == 0) {   // one leader lane per token
            const float p2 = expf(v2 - v1) * inv;
            out[tok * 2 + 0] = (float)i1;
            out[tok * 2 + 1] = (float)i2;
            out[2 * NT + tok * 2 + 0] = inv;     // p1 = exp(0)/s
            out[2 * NT + tok * 2 + 1] = p2;
            atomicAdd(&cnt[i1], 1.f);            // LDS, same-wave ordered
            atomicAdd(&cnt[i2], 1.f);
        }
        cnt_part[(size_t)blockIdx.x * E + lane] = cnt[lane];
    }
}

// ---- parallel column reduce: 128 blocks, one expert-column each ----
__global__ __launch_bounds__(256) void router_aux1(const float* __restrict__ psum_part,
                                                   const float* __restrict__ cnt_part,
                                                   float* __restrict__ sums) {
    __shared__ float buf[256];
    const int j   = blockIdx.x;      // 0..63 psum col, 64..127 cnt col
    const int tid = threadIdx.x;
    float s = 0.f;
    if (j < E) {
        for (int r = tid; r < NBLK2; r += 256) s += psum_part[(size_t)r * E + j];
    } else {
        const int e = j - E;
        for (int r = tid; r < NBLK2; r += 256) s += cnt_part[(size_t)r * E + e];
    }
    buf[tid] = s;
    __syncthreads();
    #pragma unroll
    for (int step = 128; step >= 64; step >>= 1) {
        if (tid < step) buf[tid] += buf[tid + step];
        __syncthreads();
    }
    if (tid < 64) {
        float v = buf[tid];
        #pragma unroll
        for (int off = 32; off > 0; off >>= 1) v += __shfl_down(v, off);
        if (tid == 0) sums[j] = v;
    }
}

__global__ __launch_bounds__(64) void router_aux2(const float* __restrict__ sums,
                                                  float* __restrict__ out) {
    const int e = threadIdx.x;
    float v = sums[e] * sums[E + e] * (1.0f / NT) * (1.0f / NT);
    #pragma unroll
    for (int off = 32; off > 0; off >>= 1) v += __shfl_down(v, off);
    if (e == 0) out[NT * 2 * 2] = (float)E * v;
}

extern "C" void kernel_launch(void* const* d_in, const int* in_sizes, int n_in,
                              void* d_out, int out_size, void* d_ws, size_t ws_size,
                              hipStream_t stream) {
    const float* x = (const float*)d_in[0];
    const float* W = (const float*)d_in[1];
    const float* b = (const float*)d_in[2];
    float* out = (float*)d_out;

    // ws: | wthi 256KB | wtlo 256KB | psum 256KB | cnt 256KB | sums 512B pad | part 32MB |
    char* base = (char*)d_ws;
    _Float16* wthi = (_Float16*)base;
    _Float16* wtlo = wthi + (size_t)D * E;
    float* psum_part = (float*)(base + 2 * (size_t)D * E * sizeof(_Float16));
    float* cnt_part  = psum_part + (size_t)NBLK2 * E;
    float* sums      = cnt_part + (size_t)NBLK2 * E;
    float* part      = sums + 256;

    router_prep<<<dim3(128), dim3(256), 0, stream>>>(W, wthi, wtlo);
    router_gemm<<<dim3((NT / 32) * S / 4), dim3(256), 0, stream>>>(x, wthi, wtlo, part);
    router_top<<<dim3(NBLK2), dim3(256), 0, stream>>>(part, b, out, psum_part, cnt_part);
    router_aux1<<<dim3(128), dim3(256), 0, stream>>>(psum_part, cnt_part, sums);
    router_aux2<<<dim3(1), dim3(64), 0, stream>>>(sums, out);
}